// Round 5
// baseline (592.315 us; speedup 1.0000x reference)
//
#include <hip/hip_runtime.h>
#include <hip/hip_bf16.h>
#include <stdint.h>

#define NV    40962
#define NVIN  163842
#define NB    4
#define NCIN  32
#define NCOUT 64
#define NF    81920   // 2*NV - 4

typedef __attribute__((ext_vector_type(8))) short short8;
typedef __attribute__((ext_vector_type(4))) float f32x4;

static __device__ __forceinline__ uint32_t f2bf_rne(float f) {
  uint32_t u = __float_as_uint(f);
  return (u + 0x7fffu + ((u >> 16) & 1u)) >> 16;
}
static __device__ __forceinline__ float bf_lo(uint32_t u) { return __uint_as_float(u << 16); }
static __device__ __forceinline__ float bf_hi(uint32_t u) { return __uint_as_float(u & 0xffff0000u); }

// ------- transpose x[b][c][0:V] (stride VIN) -> xt bf16 [v][b*32+c] as u32 pairs -------
__global__ __launch_bounds__(256) void k_transpose(const float* __restrict__ x,
                                                   uint32_t* __restrict__ xt32) {
  const int nvt = (NV + 63) >> 6;
  int bb = blockIdx.x / nvt;
  int v0 = (blockIdx.x % nvt) << 6;
  __shared__ float t[NCIN][65];
  int vi = threadIdx.x & 63, cg = threadIdx.x >> 6;
  int v = v0 + vi;
  for (int c = cg; c < NCIN; c += 4)
    t[c][vi] = (v < NV) ? x[(size_t)(bb * NCIN + c) * NVIN + v] : 0.f;
  __syncthreads();
  for (int i = threadIdx.x; i < 64 * 16; i += 256) {
    int v2 = i >> 4, cp = i & 15;
    int vv = v0 + v2;
    if (vv < NV)
      xt32[(size_t)vv * 64 + bb * 16 + cp] =
          (f2bf_rne(t[2 * cp + 1][v2]) << 16) | f2bf_rne(t[2 * cp][v2]);
  }
}

// ------- pack coeffs into MFMA B-fragment layout (both layers), bf16 pairs -------
__global__ __launch_bounds__(256) void k_packB(const float* __restrict__ c1,
                                               const float* __restrict__ c2,
                                               uint4* __restrict__ pb1,
                                               uint4* __restrict__ pb2) {
  // layer1: K=128, KS=4 -> 4*4*64 = 1024 uint4 ; layer2: K=256, KS=8 -> 2048 uint4
  for (int u = threadIdx.x; u < 1024; u += 256) {
    int lane = u & 63, s = (u >> 6) % 4, nt = (u >> 6) / 4;
    int o = nt * 16 + (lane & 15);
    int kb = s * 32 + (lane >> 4) * 8;
    const float* cp = c1 + o * 128 + kb;
    uint4 wv;
    wv.x = (f2bf_rne(cp[1]) << 16) | f2bf_rne(cp[0]);
    wv.y = (f2bf_rne(cp[3]) << 16) | f2bf_rne(cp[2]);
    wv.z = (f2bf_rne(cp[5]) << 16) | f2bf_rne(cp[4]);
    wv.w = (f2bf_rne(cp[7]) << 16) | f2bf_rne(cp[6]);
    pb1[u] = wv;
  }
  for (int u = threadIdx.x; u < 2048; u += 256) {
    int lane = u & 63, s = (u >> 6) % 8, nt = (u >> 6) / 8;
    int o = nt * 16 + (lane & 15);
    int kb = s * 32 + (lane >> 4) * 8;
    const float* cp = c2 + o * 256 + kb;
    uint4 wv;
    wv.x = (f2bf_rne(cp[1]) << 16) | f2bf_rne(cp[0]);
    wv.y = (f2bf_rne(cp[3]) << 16) | f2bf_rne(cp[2]);
    wv.z = (f2bf_rne(cp[5]) << 16) | f2bf_rne(cp[4]);
    wv.w = (f2bf_rne(cp[7]) << 16) | f2bf_rne(cp[6]);
    pb2[u] = wv;
  }
}

// ------- per-face grad: batched gathers + wave-uniform scalarized indices -------
template <int C>
__global__ __launch_bounds__(256) void k_grad(const uint32_t* __restrict__ xin32, // [V][BC2]
                                              const int* __restrict__ Gcol,
                                              const float* __restrict__ Gval,
                                              const float* __restrict__ EW,
                                              const float* __restrict__ NS,
                                              uint64_t* __restrict__ gg64) {     // [F][BC2]
  constexpr int BC2 = NB * C / 2;
  constexpr int FP = 256 / BC2;
  const int p = threadIdx.x % BC2;
  const int fs = threadIdx.x / BC2;
  for (int f0 = blockIdx.x * FP; f0 < NF; f0 += gridDim.x * FP) {
    int f = __builtin_amdgcn_readfirstlane(f0 + fs);  // wave-uniform (BC2 >= 64)
    int gc[9]; float gv[9];
#pragma unroll
    for (int k = 0; k < 3; ++k) {
      int r = k * NF + f;
#pragma unroll
      for (int e = 0; e < 3; ++e) {
        gc[k * 3 + e] = Gcol[r * 3 + e];
        gv[k * 3 + e] = Gval[r * 3 + e];
      }
    }
    uint32_t xs[9];
#pragma unroll
    for (int i = 0; i < 9; ++i) xs[i] = xin32[(size_t)gc[i] * BC2 + p];
    float ew[3], ns[3];
#pragma unroll
    for (int k = 0; k < 3; ++k) { ew[k] = EW[f * 3 + k]; ns[k] = NS[f * 3 + k]; }
    float e0 = 0, e1 = 0, n0 = 0, n1 = 0;
#pragma unroll
    for (int k = 0; k < 3; ++k) {
      float g0 = gv[k * 3] * bf_lo(xs[k * 3]) + gv[k * 3 + 1] * bf_lo(xs[k * 3 + 1]) +
                 gv[k * 3 + 2] * bf_lo(xs[k * 3 + 2]);
      float g1 = gv[k * 3] * bf_hi(xs[k * 3]) + gv[k * 3 + 1] * bf_hi(xs[k * 3 + 1]) +
                 gv[k * 3 + 2] * bf_hi(xs[k * 3 + 2]);
      e0 += g0 * ew[k]; n0 += g0 * ns[k];
      e1 += g1 * ew[k]; n1 += g1 * ns[k];
    }
    uint32_t a = (f2bf_rne(n0) << 16) | f2bf_rne(e0);
    uint32_t b = (f2bf_rne(n1) << 16) | f2bf_rne(e1);
    gg64[(size_t)f * BC2 + p] = ((uint64_t)b << 32) | a;
  }
}

// ------- fused vertex conv: gather->LDS A-tile (bf16, swizzled) -> MFMA einsum -------
template <int C>
__global__ __launch_bounds__(256, 6) void k_conv_mfma(
    const uint32_t* __restrict__ xin32,  // [V][BC2] bf16-pairs
    const int* __restrict__ Lcol, const float* __restrict__ Lval,
    const int* __restrict__ Fcol, const float* __restrict__ Fval,
    const uint64_t* __restrict__ gg64,   // [F][BC2]
    const uint4* __restrict__ pB,        // pre-swizzled B-fragments
    const float* __restrict__ bias,
    uint16_t* __restrict__ hout,         // [V][B*64] bf16
    float* __restrict__ bnS, float* __restrict__ bnQ) {
  constexpr int BC2 = NB * C / 2;
  constexpr int K = 4 * C;        // 128 / 256
  constexpr int K2 = 2 * K;       // bytes per A row
  constexpr int KS = K / 32;      // K-steps: 4 / 8
  constexpr int VG = (C == 64) ? 8 : 16;
  constexpr int M = 4 * VG;       // 32 / 64
  constexpr int MT = M / 16;      // 2 / 4
  constexpr int WPM = 4 / MT;     // waves per m-tile
  constexpr int NTC = MT;         // n-tiles per wave
  constexpr int VSTEP = 256 / BC2;

  __shared__ uint4 sA4[(M * K2) / 16];
  __shared__ float sS[64], sQ[64];
  if (threadIdx.x < 64) { sS[threadIdx.x] = 0.f; sQ[threadIdx.x] = 0.f; }

  const int tid = threadIdx.x;
  const int lane = tid & 63;
  const int w = tid >> 6;
  const int mtile = w / WPM;
  const int ntbase = (w % WPM) * NTC;
  const int col = lane & 15;
  const int lg = lane >> 4;

  const int p = tid % BC2;
  const int b = p / (C / 2);
  const int c0 = 2 * (p % (C / 2));
  const int vst = tid / BC2;

  float S[NTC], Q[NTC], bo[NTC];
#pragma unroll
  for (int t = 0; t < NTC; ++t) {
    S[t] = 0.f; Q[t] = 0.f;
    bo[t] = bias[(ntbase + t) * 16 + col];
  }
  __syncthreads();

  char* sA = (char*)sA4;
  const int npass = (NV + VG - 1) / VG;

  for (int it = blockIdx.x; it < npass; it += gridDim.x) {
    const int v0 = it * VG;
    // ---- gather phase: build A[m][k] bf16, m = vl*4+b, k = c*4 + {id,lap,ew,ns} ----
#pragma unroll
    for (int step = 0; step < VG / VSTEP; ++step) {
      int vl = step * VSTEP + vst;
      int v = v0 + vl;
      int m = vl * 4 + b;
      uint4 outv = {0u, 0u, 0u, 0u};
      if (v < NV) {
        int vu = __builtin_amdgcn_readfirstlane(v);  // wave-uniform (BC2 >= 64)
        uint32_t uid = xin32[(size_t)vu * BC2 + p];
        int lc[7]; float lw[7];
#pragma unroll
        for (int d = 0; d < 7; ++d) { lc[d] = Lcol[vu * 7 + d]; lw[d] = Lval[vu * 7 + d]; }
        uint32_t lx[7];
#pragma unroll
        for (int d = 0; d < 7; ++d) lx[d] = xin32[(size_t)lc[d] * BC2 + p];
        int fc[6]; float fw[6];
#pragma unroll
        for (int d = 0; d < 6; ++d) { fc[d] = Fcol[vu * 6 + d]; fw[d] = Fval[vu * 6 + d]; }
        uint64_t gx[6];
#pragma unroll
        for (int d = 0; d < 6; ++d) gx[d] = gg64[(size_t)fc[d] * BC2 + p];

        float l0 = 0.f, l1 = 0.f;
#pragma unroll
        for (int d = 0; d < 7; ++d) { l0 += lw[d] * bf_lo(lx[d]); l1 += lw[d] * bf_hi(lx[d]); }
        float e0 = 0, e1 = 0, n0 = 0, n1 = 0;
#pragma unroll
        for (int d = 0; d < 6; ++d) {
          uint32_t ga = (uint32_t)gx[d], gb = (uint32_t)(gx[d] >> 32);
          e0 += fw[d] * bf_lo(ga); n0 += fw[d] * bf_hi(ga);
          e1 += fw[d] * bf_lo(gb); n1 += fw[d] * bf_hi(gb);
        }
        outv.x = (f2bf_rne(l0) << 16) | (uid & 0xffffu);
        outv.y = (f2bf_rne(n0) << 16) | f2bf_rne(e0);
        outv.z = (f2bf_rne(l1) << 16) | (uid >> 16);
        outv.w = (f2bf_rne(n1) << 16) | f2bf_rne(e1);
      }
      int byteoff = m * K2 + ((c0 * 8) ^ ((m & 7) << 4));
      *(uint4*)(sA + byteoff) = outv;
    }
    __syncthreads();

    // ---- MFMA phase: D[m][o] = A[m][k] * coeffs^T[k][o] ----
    f32x4 acc[NTC];
#pragma unroll
    for (int t = 0; t < NTC; ++t) acc[t] = (f32x4){0.f, 0.f, 0.f, 0.f};
    const int marow = mtile * 16 + col;
    const int abase = marow * K2;
    const int aswz = (marow & 7) << 4;
#pragma unroll
    for (int s = 0; s < KS; ++s) {
      int kb = s * 32 + lg * 8;
      short8 af = *(const short8*)(sA + abase + ((kb * 2) ^ aswz));
#pragma unroll
      for (int t = 0; t < NTC; ++t) {
        short8 bf = *(const short8*)(pB + ((ntbase + t) * KS + s) * 64 + lane);
        acc[t] = __builtin_amdgcn_mfma_f32_16x16x32_bf16(af, bf, acc[t], 0, 0, 0);
      }
    }

    // ---- epilogue: bias, bf16 store, BN partial sums ----
#pragma unroll
    for (int t = 0; t < NTC; ++t) {
      int o = (ntbase + t) * 16 + col;
#pragma unroll
      for (int r = 0; r < 4; ++r) {
        int m = mtile * 16 + lg * 4 + r;
        int vl = m >> 2, b2 = m & 3;
        int v = v0 + vl;
        if (v < NV) {
          float h = acc[t][r] + bo[t];
          hout[((size_t)v * 4 + b2) * 64 + o] = (uint16_t)f2bf_rne(h);
          S[t] += h;
          Q[t] += h * h;
        }
      }
    }
    __syncthreads();
  }

#pragma unroll
  for (int t = 0; t < NTC; ++t) {
    int o = (ntbase + t) * 16 + col;
    atomicAdd(&sS[o], S[t]);
    atomicAdd(&sQ[o], Q[t]);
  }
  __syncthreads();
  if (threadIdx.x < 64) {
    atomicAdd(&bnS[threadIdx.x], sS[threadIdx.x]);
    atomicAdd(&bnQ[threadIdx.x], sQ[threadIdx.x]);
  }
}

// ---------------- BN stats -> scale/shift ----------------
__global__ void k_bnfin(const float* __restrict__ S, const float* __restrict__ Q,
                        const float* __restrict__ gamma, const float* __restrict__ beta,
                        float* __restrict__ scale, float* __restrict__ shift) {
  int o = threadIdx.x;
  if (o < NCOUT) {
    const float n = (float)((size_t)NB * NV);
    float mu = S[o] / n;
    float var = Q[o] / n - mu * mu;
    float sc = gamma[o] * rsqrtf(var + 1e-5f);
    scale[o] = sc;
    shift[o] = beta[o] - mu * sc;
  }
}

// ------------- in-place BN apply + relu on bf16 h1 (uint4 = 8 bf16) -------------
__global__ __launch_bounds__(256) void k_apply(uint32_t* __restrict__ h,
                                               const float* __restrict__ scale,
                                               const float* __restrict__ shift) {
  const int N = NV * 32;  // uint4 count: V*256 bf16 / 8
  for (int i = blockIdx.x * 256 + threadIdx.x; i < N; i += gridDim.x * 256) {
    uint4 u = ((uint4*)h)[i];
    int o0 = (i * 8) & 63;
    uint32_t* uu = &u.x;
#pragma unroll
    for (int j = 0; j < 4; ++j) {
      float lo = fmaxf(0.f, bf_lo(uu[j]) * scale[o0 + 2 * j] + shift[o0 + 2 * j]);
      float hi = fmaxf(0.f, bf_hi(uu[j]) * scale[o0 + 2 * j + 1] + shift[o0 + 2 * j + 1]);
      uu[j] = (f2bf_rne(hi) << 16) | f2bf_rne(lo);
    }
    ((uint4*)h)[i] = u;
  }
}

// -------- BN apply + relu + transpose to [B][O][V], FLOAT32 output --------
__global__ __launch_bounds__(256) void k_final(const uint16_t* __restrict__ h2,
                                               const float* __restrict__ scale,
                                               const float* __restrict__ shift,
                                               float* __restrict__ out) {
  const int nvt = (NV + 63) >> 6;
  int b = blockIdx.x / nvt;
  int v0 = (blockIdx.x % nvt) << 6;
  __shared__ float t[64][65];
  int o = threadIdx.x & 63, vg = threadIdx.x >> 6;
  float sc = scale[o], sh = shift[o];
  for (int vi = vg; vi < 64; vi += 4) {
    int v = v0 + vi;
    float val = 0.f;
    if (v < NV) {
      uint32_t u = h2[(size_t)v * (NB * NCOUT) + b * NCOUT + o];
      val = __uint_as_float(u << 16);
    }
    t[o][vi] = fmaxf(0.f, val * sc + sh);
  }
  __syncthreads();
  int vi2 = threadIdx.x & 63, og = threadIdx.x >> 6;
  int v = v0 + vi2;
  for (int o2 = og; o2 < 64; o2 += 4) {
    if (v < NV) out[((size_t)b * NCOUT + o2) * NV + v] = t[o2][vi2];
  }
}

extern "C" void kernel_launch(void* const* d_in, const int* in_sizes, int n_in,
                              void* d_out, int out_size, void* d_ws, size_t ws_size,
                              hipStream_t stream) {
  const float* x       = (const float*)d_in[0];
  const int*   Lcol    = (const int*)d_in[2];
  const float* Lval    = (const float*)d_in[3];
  const int*   Gcol    = (const int*)d_in[5];
  const float* Gval    = (const float*)d_in[6];
  const int*   Fcol    = (const int*)d_in[8];
  const float* Fval    = (const float*)d_in[9];
  const float* EW      = (const float*)d_in[10];
  const float* NS      = (const float*)d_in[11];
  const float* coeffs1 = (const float*)d_in[12];
  const float* bias1   = (const float*)d_in[13];
  const float* gamma1  = (const float*)d_in[14];
  const float* beta1   = (const float*)d_in[15];
  const float* coeffs2 = (const float*)d_in[16];
  const float* bias2   = (const float*)d_in[17];
  const float* gamma2  = (const float*)d_in[18];
  const float* beta2   = (const float*)d_in[19];
  float* out           = (float*)d_out;   // reference output dtype is float32

  // ws layout (~137 MB):
  //   xt : V*64 u32  (bf16 [V][128])   = 10.49 MB
  //   gg : F*128 u64                   = 83.89 MB
  //   h1 : V*128 u32 (bf16 [V][256])   = 20.97 MB
  //   h2 : V*128 u32 (bf16 [V][256])   = 20.97 MB
  //   st : 512 f32 ; pb1 : 1024 uint4 ; pb2 : 2048 uint4
  uint32_t* xt = (uint32_t*)d_ws;
  uint64_t* gg = (uint64_t*)(xt + (size_t)NV * 64);
  uint32_t* h1 = (uint32_t*)(gg + (size_t)NF * 128);
  uint32_t* h2 = h1 + (size_t)NV * 128;
  float*    st = (float*)(h2 + (size_t)NV * 128);
  uint4*    pb1 = (uint4*)(st + 512);
  uint4*    pb2 = pb1 + 1024;
  float *S1 = st, *Q1 = st + 64, *S2 = st + 128, *Q2 = st + 192;
  float *sc1 = st + 256, *sh1 = st + 320, *sc2 = st + 384, *sh2 = st + 448;

  hipMemsetAsync(st, 0, 256 * sizeof(float), stream);

  const int nvt = (NV + 63) >> 6;
  k_packB<<<1, 256, 0, stream>>>(coeffs1, coeffs2, pb1, pb2);
  k_transpose<<<NB * nvt, 256, 0, stream>>>(x, xt);

  // ---- layer 1 (C = 32) ----
  k_grad<NCIN><<<2048, 256, 0, stream>>>(xt, Gcol, Gval, EW, NS, gg);
  k_conv_mfma<NCIN><<<2048, 256, 0, stream>>>(xt, Lcol, Lval, Fcol, Fval, gg,
                                              pb1, bias1, (uint16_t*)h1, S1, Q1);
  k_bnfin<<<1, 64, 0, stream>>>(S1, Q1, gamma1, beta1, sc1, sh1);
  k_apply<<<2048, 256, 0, stream>>>(h1, sc1, sh1);

  // ---- layer 2 (C = 64) ----
  k_grad<NCOUT><<<2048, 256, 0, stream>>>(h1, Gcol, Gval, EW, NS, gg);
  k_conv_mfma<NCOUT><<<2048, 256, 0, stream>>>(h1, Lcol, Lval, Fcol, Fval, gg,
                                               pb2, bias2, (uint16_t*)h2, S2, Q2);
  k_bnfin<<<1, 64, 0, stream>>>(S2, Q2, gamma2, beta2, sc2, sh2);
  k_final<<<NB * nvt, 256, 0, stream>>>((const uint16_t*)h2, sc2, sh2, out);
}

// Round 6
// 488.219 us; speedup vs baseline: 1.2132x; 1.2132x over previous
//
#include <hip/hip_runtime.h>
#include <hip/hip_bf16.h>
#include <stdint.h>

#define NV    40962
#define NVIN  163842
#define NB    4
#define NCIN  32
#define NCOUT 64
#define NF    81920   // 2*NV - 4

typedef __attribute__((ext_vector_type(8))) short short8;
typedef __attribute__((ext_vector_type(4))) float f32x4;

static __device__ __forceinline__ uint32_t f2bf_rne(float f) {
  uint32_t u = __float_as_uint(f);
  return (u + 0x7fffu + ((u >> 16) & 1u)) >> 16;
}
static __device__ __forceinline__ float bf_lo(uint32_t u) { return __uint_as_float(u << 16); }
static __device__ __forceinline__ float bf_hi(uint32_t u) { return __uint_as_float(u & 0xffff0000u); }

// ------- transpose x[b][c][0:V] (stride VIN) -> xt bf16 [v][b*32+c] as u32 pairs -------
__global__ __launch_bounds__(256) void k_transpose(const float* __restrict__ x,
                                                   uint32_t* __restrict__ xt32) {
  const int nvt = (NV + 63) >> 6;
  int bb = blockIdx.x / nvt;
  int v0 = (blockIdx.x % nvt) << 6;
  __shared__ float t[NCIN][65];
  int vi = threadIdx.x & 63, cg = threadIdx.x >> 6;
  int v = v0 + vi;
  for (int c = cg; c < NCIN; c += 4)
    t[c][vi] = (v < NV) ? x[(size_t)(bb * NCIN + c) * NVIN + v] : 0.f;
  __syncthreads();
  for (int i = threadIdx.x; i < 64 * 16; i += 256) {
    int v2 = i >> 4, cp = i & 15;
    int vv = v0 + v2;
    if (vv < NV)
      xt32[(size_t)vv * 64 + bb * 16 + cp] =
          (f2bf_rne(t[2 * cp + 1][v2]) << 16) | f2bf_rne(t[2 * cp][v2]);
  }
}

// ------- pack coeffs into MFMA B-fragment layout (both layers), bf16 pairs -------
__global__ __launch_bounds__(256) void k_packB(const float* __restrict__ c1,
                                               const float* __restrict__ c2,
                                               uint4* __restrict__ pb1,
                                               uint4* __restrict__ pb2) {
  for (int u = threadIdx.x; u < 1024; u += 256) {
    int lane = u & 63, s = (u >> 6) % 4, nt = (u >> 6) / 4;
    int o = nt * 16 + (lane & 15);
    int kb = s * 32 + (lane >> 4) * 8;
    const float* cp = c1 + o * 128 + kb;
    uint4 wv;
    wv.x = (f2bf_rne(cp[1]) << 16) | f2bf_rne(cp[0]);
    wv.y = (f2bf_rne(cp[3]) << 16) | f2bf_rne(cp[2]);
    wv.z = (f2bf_rne(cp[5]) << 16) | f2bf_rne(cp[4]);
    wv.w = (f2bf_rne(cp[7]) << 16) | f2bf_rne(cp[6]);
    pb1[u] = wv;
  }
  for (int u = threadIdx.x; u < 2048; u += 256) {
    int lane = u & 63, s = (u >> 6) % 8, nt = (u >> 6) / 8;
    int o = nt * 16 + (lane & 15);
    int kb = s * 32 + (lane >> 4) * 8;
    const float* cp = c2 + o * 256 + kb;
    uint4 wv;
    wv.x = (f2bf_rne(cp[1]) << 16) | f2bf_rne(cp[0]);
    wv.y = (f2bf_rne(cp[3]) << 16) | f2bf_rne(cp[2]);
    wv.z = (f2bf_rne(cp[5]) << 16) | f2bf_rne(cp[4]);
    wv.w = (f2bf_rne(cp[7]) << 16) | f2bf_rne(cp[6]);
    pb2[u] = wv;
  }
}

// ------- per-face grad: batched gathers + wave-uniform scalarized indices -------
template <int C>
__global__ __launch_bounds__(256) void k_grad(const uint32_t* __restrict__ xin32, // [V][BC2]
                                              const int* __restrict__ Gcol,
                                              const float* __restrict__ Gval,
                                              const float* __restrict__ EW,
                                              const float* __restrict__ NS,
                                              uint64_t* __restrict__ gg64) {     // [F][BC2]
  constexpr int BC2 = NB * C / 2;
  constexpr int FP = 256 / BC2;
  const int p = threadIdx.x % BC2;
  const int fs = threadIdx.x / BC2;
  for (int f0 = blockIdx.x * FP; f0 < NF; f0 += gridDim.x * FP) {
    int f = __builtin_amdgcn_readfirstlane(f0 + fs);  // wave-uniform (BC2 >= 64)
    int gc[9]; float gv[9];
#pragma unroll
    for (int k = 0; k < 3; ++k) {
      int r = k * NF + f;
#pragma unroll
      for (int e = 0; e < 3; ++e) {
        gc[k * 3 + e] = Gcol[r * 3 + e];
        gv[k * 3 + e] = Gval[r * 3 + e];
      }
    }
    uint32_t xs[9];
#pragma unroll
    for (int i = 0; i < 9; ++i) xs[i] = xin32[(size_t)gc[i] * BC2 + p];
    float ew[3], ns[3];
#pragma unroll
    for (int k = 0; k < 3; ++k) { ew[k] = EW[f * 3 + k]; ns[k] = NS[f * 3 + k]; }
    float e0 = 0, e1 = 0, n0 = 0, n1 = 0;
#pragma unroll
    for (int k = 0; k < 3; ++k) {
      float g0 = gv[k * 3] * bf_lo(xs[k * 3]) + gv[k * 3 + 1] * bf_lo(xs[k * 3 + 1]) +
                 gv[k * 3 + 2] * bf_lo(xs[k * 3 + 2]);
      float g1 = gv[k * 3] * bf_hi(xs[k * 3]) + gv[k * 3 + 1] * bf_hi(xs[k * 3 + 1]) +
                 gv[k * 3 + 2] * bf_hi(xs[k * 3 + 2]);
      e0 += g0 * ew[k]; n0 += g0 * ns[k];
      e1 += g1 * ew[k]; n1 += g1 * ns[k];
    }
    uint32_t a = (f2bf_rne(n0) << 16) | f2bf_rne(e0);
    uint32_t b = (f2bf_rne(n1) << 16) | f2bf_rne(e1);
    gg64[(size_t)f * BC2 + p] = ((uint64_t)b << 32) | a;
  }
}

// ------- fused vertex conv: gather->LDS A-tile (bf16, swizzled) -> MFMA einsum -------
template <int C>
__global__ __launch_bounds__(256, 4) void k_conv_mfma(
    const uint32_t* __restrict__ xin32,  // [V][BC2] bf16-pairs
    const int* __restrict__ Lcol, const float* __restrict__ Lval,
    const int* __restrict__ Fcol, const float* __restrict__ Fval,
    const uint64_t* __restrict__ gg64,   // [F][BC2]
    const uint4* __restrict__ pB,        // pre-swizzled B-fragments
    const float* __restrict__ bias,
    uint16_t* __restrict__ hout,         // [V][B*64] bf16
    float* __restrict__ bnS, float* __restrict__ bnQ) {
  constexpr int BC2 = NB * C / 2;
  constexpr int K = 4 * C;        // 128 / 256
  constexpr int K2 = 2 * K;       // bytes per A row
  constexpr int KS = K / 32;      // K-steps: 4 / 8
  constexpr int VG = (C == 64) ? 8 : 16;
  constexpr int M = 4 * VG;       // 32 / 64
  constexpr int MT = M / 16;      // 2 / 4
  constexpr int WPM = 4 / MT;     // waves per m-tile
  constexpr int NTC = MT;         // n-tiles per wave
  constexpr int VSTEP = 256 / BC2;

  __shared__ uint4 sA4[(M * K2) / 16];
  __shared__ float sS[64], sQ[64];
  if (threadIdx.x < 64) { sS[threadIdx.x] = 0.f; sQ[threadIdx.x] = 0.f; }

  const int tid = threadIdx.x;
  const int lane = tid & 63;
  const int w = tid >> 6;
  const int mtile = w / WPM;
  const int ntbase = (w % WPM) * NTC;
  const int col = lane & 15;
  const int lg = lane >> 4;

  const int p = tid % BC2;
  const int b = p / (C / 2);
  const int c0 = 2 * (p % (C / 2));
  const int vst = tid / BC2;

  float S[NTC], Q[NTC], bo[NTC];
#pragma unroll
  for (int t = 0; t < NTC; ++t) {
    S[t] = 0.f; Q[t] = 0.f;
    bo[t] = bias[(ntbase + t) * 16 + col];
  }
  __syncthreads();

  char* sA = (char*)sA4;
  const int npass = (NV + VG - 1) / VG;

  for (int it = blockIdx.x; it < npass; it += gridDim.x) {
    const int v0 = it * VG;
    // ---- gather phase: build A[m][k] bf16, m = vl*4+b, k = c*4 + {id,lap,ew,ns} ----
#pragma unroll
    for (int step = 0; step < VG / VSTEP; ++step) {
      int vl = step * VSTEP + vst;
      int v = v0 + vl;
      int m = vl * 4 + b;
      uint4 outv = {0u, 0u, 0u, 0u};
      if (v < NV) {
        int vu = __builtin_amdgcn_readfirstlane(v);  // wave-uniform (BC2 >= 64)
        uint32_t uid = xin32[(size_t)vu * BC2 + p];
        // --- L phase (short live range) ---
        float l0 = 0.f, l1 = 0.f;
        {
          int lc[7]; float lw[7];
#pragma unroll
          for (int d = 0; d < 7; ++d) { lc[d] = Lcol[vu * 7 + d]; lw[d] = Lval[vu * 7 + d]; }
          uint32_t lx[7];
#pragma unroll
          for (int d = 0; d < 7; ++d) lx[d] = xin32[(size_t)lc[d] * BC2 + p];
#pragma unroll
          for (int d = 0; d < 7; ++d) { l0 += lw[d] * bf_lo(lx[d]); l1 += lw[d] * bf_hi(lx[d]); }
        }
        // --- F phase ---
        float e0 = 0, e1 = 0, n0 = 0, n1 = 0;
        {
          int fc[6]; float fw[6];
#pragma unroll
          for (int d = 0; d < 6; ++d) { fc[d] = Fcol[vu * 6 + d]; fw[d] = Fval[vu * 6 + d]; }
          uint64_t gx[6];
#pragma unroll
          for (int d = 0; d < 6; ++d) gx[d] = gg64[(size_t)fc[d] * BC2 + p];
#pragma unroll
          for (int d = 0; d < 6; ++d) {
            uint32_t ga = (uint32_t)gx[d], gb = (uint32_t)(gx[d] >> 32);
            e0 += fw[d] * bf_lo(ga); n0 += fw[d] * bf_hi(ga);
            e1 += fw[d] * bf_lo(gb); n1 += fw[d] * bf_hi(gb);
          }
        }
        outv.x = (f2bf_rne(l0) << 16) | (uid & 0xffffu);
        outv.y = (f2bf_rne(n0) << 16) | f2bf_rne(e0);
        outv.z = (f2bf_rne(l1) << 16) | (uid >> 16);
        outv.w = (f2bf_rne(n1) << 16) | f2bf_rne(e1);
      }
      int byteoff = m * K2 + ((c0 * 8) ^ ((m & 7) << 4));
      *(uint4*)(sA + byteoff) = outv;
    }
    __syncthreads();

    // ---- MFMA phase: D[m][o] = A[m][k] * coeffs^T[k][o] ----
    f32x4 acc[NTC];
#pragma unroll
    for (int t = 0; t < NTC; ++t) acc[t] = (f32x4){0.f, 0.f, 0.f, 0.f};
    const int marow = mtile * 16 + col;
    const int abase = marow * K2;
    const int aswz = (marow & 7) << 4;
#pragma unroll
    for (int s = 0; s < KS; ++s) {
      int kb = s * 32 + lg * 8;
      short8 af = *(const short8*)(sA + abase + ((kb * 2) ^ aswz));
#pragma unroll
      for (int t = 0; t < NTC; ++t) {
        short8 bf = *(const short8*)(pB + ((ntbase + t) * KS + s) * 64 + lane);
        acc[t] = __builtin_amdgcn_mfma_f32_16x16x32_bf16(af, bf, acc[t], 0, 0, 0);
      }
    }

    // ---- epilogue: bias, bf16 store, BN partial sums ----
#pragma unroll
    for (int t = 0; t < NTC; ++t) {
      int o = (ntbase + t) * 16 + col;
#pragma unroll
      for (int r = 0; r < 4; ++r) {
        int m = mtile * 16 + lg * 4 + r;
        int vl = m >> 2, b2 = m & 3;
        int v = v0 + vl;
        if (v < NV) {
          float h = acc[t][r] + bo[t];
          hout[((size_t)v * 4 + b2) * 64 + o] = (uint16_t)f2bf_rne(h);
          S[t] += h;
          Q[t] += h * h;
        }
      }
    }
    __syncthreads();
  }

#pragma unroll
  for (int t = 0; t < NTC; ++t) {
    int o = (ntbase + t) * 16 + col;
    atomicAdd(&sS[o], S[t]);
    atomicAdd(&sQ[o], Q[t]);
  }
  __syncthreads();
  if (threadIdx.x < 64) {
    atomicAdd(&bnS[threadIdx.x], sS[threadIdx.x]);
    atomicAdd(&bnQ[threadIdx.x], sQ[threadIdx.x]);
  }
}

// ---------------- BN stats -> scale/shift ----------------
__global__ void k_bnfin(const float* __restrict__ S, const float* __restrict__ Q,
                        const float* __restrict__ gamma, const float* __restrict__ beta,
                        float* __restrict__ scale, float* __restrict__ shift) {
  int o = threadIdx.x;
  if (o < NCOUT) {
    const float n = (float)((size_t)NB * NV);
    float mu = S[o] / n;
    float var = Q[o] / n - mu * mu;
    float sc = gamma[o] * rsqrtf(var + 1e-5f);
    scale[o] = sc;
    shift[o] = beta[o] - mu * sc;
  }
}

// ------------- in-place BN apply + relu on bf16 h1 (uint4 = 8 bf16) -------------
__global__ __launch_bounds__(256) void k_apply(uint32_t* __restrict__ h,
                                               const float* __restrict__ scale,
                                               const float* __restrict__ shift) {
  const int N = NV * 32;  // uint4 count: V*256 bf16 / 8
  for (int i = blockIdx.x * 256 + threadIdx.x; i < N; i += gridDim.x * 256) {
    uint4 u = ((uint4*)h)[i];
    int o0 = (i * 8) & 63;
    uint32_t* uu = &u.x;
#pragma unroll
    for (int j = 0; j < 4; ++j) {
      float lo = fmaxf(0.f, bf_lo(uu[j]) * scale[o0 + 2 * j] + shift[o0 + 2 * j]);
      float hi = fmaxf(0.f, bf_hi(uu[j]) * scale[o0 + 2 * j + 1] + shift[o0 + 2 * j + 1]);
      uu[j] = (f2bf_rne(hi) << 16) | f2bf_rne(lo);
    }
    ((uint4*)h)[i] = u;
  }
}

// -------- BN apply + relu + transpose to [B][O][V], FLOAT32 output --------
__global__ __launch_bounds__(256) void k_final(const uint16_t* __restrict__ h2,
                                               const float* __restrict__ scale,
                                               const float* __restrict__ shift,
                                               float* __restrict__ out) {
  const int nvt = (NV + 63) >> 6;
  int b = blockIdx.x / nvt;
  int v0 = (blockIdx.x % nvt) << 6;
  __shared__ float t[64][65];
  int o = threadIdx.x & 63, vg = threadIdx.x >> 6;
  float sc = scale[o], sh = shift[o];
  for (int vi = vg; vi < 64; vi += 4) {
    int v = v0 + vi;
    float val = 0.f;
    if (v < NV) {
      uint32_t u = h2[(size_t)v * (NB * NCOUT) + b * NCOUT + o];
      val = __uint_as_float(u << 16);
    }
    t[o][vi] = fmaxf(0.f, val * sc + sh);
  }
  __syncthreads();
  int vi2 = threadIdx.x & 63, og = threadIdx.x >> 6;
  int v = v0 + vi2;
  for (int o2 = og; o2 < 64; o2 += 4) {
    if (v < NV) out[((size_t)b * NCOUT + o2) * NV + v] = t[o2][vi2];
  }
}

extern "C" void kernel_launch(void* const* d_in, const int* in_sizes, int n_in,
                              void* d_out, int out_size, void* d_ws, size_t ws_size,
                              hipStream_t stream) {
  const float* x       = (const float*)d_in[0];
  const int*   Lcol    = (const int*)d_in[2];
  const float* Lval    = (const float*)d_in[3];
  const int*   Gcol    = (const int*)d_in[5];
  const float* Gval    = (const float*)d_in[6];
  const int*   Fcol    = (const int*)d_in[8];
  const float* Fval    = (const float*)d_in[9];
  const float* EW      = (const float*)d_in[10];
  const float* NS      = (const float*)d_in[11];
  const float* coeffs1 = (const float*)d_in[12];
  const float* bias1   = (const float*)d_in[13];
  const float* gamma1  = (const float*)d_in[14];
  const float* beta1   = (const float*)d_in[15];
  const float* coeffs2 = (const float*)d_in[16];
  const float* bias2   = (const float*)d_in[17];
  const float* gamma2  = (const float*)d_in[18];
  const float* beta2   = (const float*)d_in[19];
  float* out           = (float*)d_out;   // reference output dtype is float32

  uint32_t* xt = (uint32_t*)d_ws;
  uint64_t* gg = (uint64_t*)(xt + (size_t)NV * 64);
  uint32_t* h1 = (uint32_t*)(gg + (size_t)NF * 128);
  uint32_t* h2 = h1 + (size_t)NV * 128;
  float*    st = (float*)(h2 + (size_t)NV * 128);
  uint4*    pb1 = (uint4*)(st + 512);
  uint4*    pb2 = pb1 + 1024;
  float *S1 = st, *Q1 = st + 64, *S2 = st + 128, *Q2 = st + 192;
  float *sc1 = st + 256, *sh1 = st + 320, *sc2 = st + 384, *sh2 = st + 448;

  hipMemsetAsync(st, 0, 256 * sizeof(float), stream);

  const int nvt = (NV + 63) >> 6;
  k_packB<<<1, 256, 0, stream>>>(coeffs1, coeffs2, pb1, pb2);
  k_transpose<<<NB * nvt, 256, 0, stream>>>(x, xt);

  // ---- layer 1 (C = 32) ----
  k_grad<NCIN><<<2048, 256, 0, stream>>>(xt, Gcol, Gval, EW, NS, gg);
  k_conv_mfma<NCIN><<<2048, 256, 0, stream>>>(xt, Lcol, Lval, Fcol, Fval, gg,
                                              pb1, bias1, (uint16_t*)h1, S1, Q1);
  k_bnfin<<<1, 64, 0, stream>>>(S1, Q1, gamma1, beta1, sc1, sh1);
  k_apply<<<2048, 256, 0, stream>>>(h1, sc1, sh1);

  // ---- layer 2 (C = 64) ----
  k_grad<NCOUT><<<2048, 256, 0, stream>>>(h1, Gcol, Gval, EW, NS, gg);
  k_conv_mfma<NCOUT><<<2048, 256, 0, stream>>>(h1, Lcol, Lval, Fcol, Fval, gg,
                                               pb2, bias2, (uint16_t*)h2, S2, Q2);
  k_bnfin<<<1, 64, 0, stream>>>(S2, Q2, gamma2, beta2, sc2, sh2);
  k_final<<<NB * nvt, 256, 0, stream>>>((const uint16_t*)h2, sc2, sh2, out);
}